// Round 5
// baseline (210.154 us; speedup 1.0000x reference)
//
#include <hip/hip_runtime.h>
#include <hip/hip_cooperative_groups.h>
#include <math.h>

namespace cg = cooperative_groups;

// SE block: x[32,512,56,56] fp32, fused single-pass cooperative kernel.
// Per CU: 64 rows of x (802 KB fp32) retained on-chip as fp16 (401 KB):
//   2 rows/wave in LDS (16 rows, 100 KB) + 6 rows/wave in VGPRs (156 regs).
// Phase 1: read x once (205 MB), fp16-retain, row sums -> sq (global).
// grid.sync() ; Phase 2: tiny FCs -> e (LDS). Phase 3: scale retained x,
// nt-store out (205 MB). HBM total 411 MB vs 616 MB for the 3-kernel version.

#define SE_C 512
#define SE_CR 32
#define SPATIAL 3136
#define VEC_PER_ROW 784          // f4 per (b,c) row
#define ROWS 16384
#define NBLK 256
#define NTHR 512                 // 8 waves
#define ROWS_PER_BLK 64
#define ROWS_PER_WAVE 8
#define LDS_ROWS_PER_WAVE 2
#define REG_ROWS_PER_WAVE 6
#define LDS_ROWS 16              // 8 waves * 2
#define K_FULL 12                // 12*64 = 768 f4; tail f4 768..783 on lanes 0..15

typedef float f4 __attribute__((ext_vector_type(4)));
typedef _Float16 h4 __attribute__((ext_vector_type(4)));

#define LDS_X_BYTES (LDS_ROWS * VEC_PER_ROW * 8)              // 100352
#define LDS_TOTAL   (LDS_X_BYTES + SE_C*4 + SE_CR*4 + ROWS_PER_BLK*4)

__global__ __launch_bounds__(NTHR, 2) void se_fused(
    const f4* __restrict__ x,
    const float* __restrict__ w1, const float* __restrict__ b1,
    const float* __restrict__ w2, const float* __restrict__ b2,
    float* __restrict__ sq_g, f4* __restrict__ out)
{
    extern __shared__ char smem[];
    h4*    xl     = (h4*)smem;                                  // [16][784]
    float* sq_lds = (float*)(smem + LDS_X_BYTES);               // [512]
    float* h_lds  = sq_lds + SE_C;                              // [32]
    float* e_lds  = h_lds + SE_CR;                              // [64]

    const int t    = threadIdx.x;
    const int wave = t >> 6;
    const int lane = t & 63;
    const int blk  = blockIdx.x;
    const int row0 = blk * ROWS_PER_BLK + wave * ROWS_PER_WAVE;

    h4 rx[REG_ROWS_PER_WAVE][K_FULL + 1];   // statically indexed only

    // ---------------- phase 1: read x once, retain fp16, row sums ----------
    #pragma unroll
    for (int r = 0; r < ROWS_PER_WAVE; ++r) {
        const int row = row0 + r;
        const f4* p = x + (size_t)row * VEC_PER_ROW;
        float s = 0.f;
        if (r < LDS_ROWS_PER_WAVE) {
            h4* q = xl + (size_t)(wave * LDS_ROWS_PER_WAVE + r) * VEC_PER_ROW;
            #pragma unroll
            for (int k = 0; k <= K_FULL; ++k) {
                const int i = lane + (k << 6);
                if (k < K_FULL || lane < 16) {
                    f4 v = __builtin_nontemporal_load(p + i);
                    s += (v.x + v.y) + (v.z + v.w);
                    h4 h;
                    h.x = (_Float16)v.x; h.y = (_Float16)v.y;
                    h.z = (_Float16)v.z; h.w = (_Float16)v.w;
                    q[i] = h;
                }
            }
        } else {
            const int rr = r - LDS_ROWS_PER_WAVE;               // 0..5 static
            #pragma unroll
            for (int k = 0; k <= K_FULL; ++k) {
                const int i = lane + (k << 6);
                if (k < K_FULL || lane < 16) {
                    f4 v = __builtin_nontemporal_load(p + i);
                    s += (v.x + v.y) + (v.z + v.w);
                    h4 h;
                    h.x = (_Float16)v.x; h.y = (_Float16)v.y;
                    h.z = (_Float16)v.z; h.w = (_Float16)v.w;
                    rx[rr][k] = h;
                }
            }
        }
        #pragma unroll
        for (int off = 32; off > 0; off >>= 1) s += __shfl_down(s, off, 64);
        if (lane == 0) sq_g[row] = s * (1.0f / (float)SPATIAL);
    }

    // sq must be visible across XCDs after the grid barrier
    __builtin_amdgcn_fence(__ATOMIC_RELEASE, "agent");
    cg::this_grid().sync();
    __builtin_amdgcn_fence(__ATOMIC_ACQUIRE, "agent");

    // ---------------- phase 2: excitation (redundant per block) ------------
    const int b = blk >> 3;                     // batch of this block's rows
    sq_lds[t] = sq_g[b * SE_C + t];
    __syncthreads();
    if (t < SE_CR) {
        float acc = b1[t];
        const float* wr = w1 + t * SE_C;
        #pragma unroll 8
        for (int c = 0; c < SE_C; ++c) acc += sq_lds[c] * wr[c];
        h_lds[t] = fmaxf(acc, 0.f);
    }
    __syncthreads();
    if (t < ROWS_PER_BLK) {
        const int c = (blk & 7) * ROWS_PER_BLK + t;   // channel of local row t
        float acc = b2[c];
        const float* wr = w2 + c * SE_CR;
        #pragma unroll
        for (int j = 0; j < SE_CR; ++j) acc += h_lds[j] * wr[j];
        e_lds[t] = 1.0f / (1.0f + expf(-acc));
    }
    __syncthreads();

    // ---------------- phase 3: scale retained x, nt-store out --------------
    #pragma unroll
    for (int r = 0; r < ROWS_PER_WAVE; ++r) {
        const int row = row0 + r;
        const float s = e_lds[wave * ROWS_PER_WAVE + r];
        f4* po = out + (size_t)row * VEC_PER_ROW;
        if (r < LDS_ROWS_PER_WAVE) {
            const h4* q = xl + (size_t)(wave * LDS_ROWS_PER_WAVE + r) * VEC_PER_ROW;
            #pragma unroll
            for (int k = 0; k <= K_FULL; ++k) {
                const int i = lane + (k << 6);
                if (k < K_FULL || lane < 16) {
                    h4 h = q[i];
                    f4 o;
                    o.x = (float)h.x * s; o.y = (float)h.y * s;
                    o.z = (float)h.z * s; o.w = (float)h.w * s;
                    __builtin_nontemporal_store(o, po + i);
                }
            }
        } else {
            const int rr = r - LDS_ROWS_PER_WAVE;
            #pragma unroll
            for (int k = 0; k <= K_FULL; ++k) {
                const int i = lane + (k << 6);
                if (k < K_FULL || lane < 16) {
                    h4 h = rx[rr][k];
                    f4 o;
                    o.x = (float)h.x * s; o.y = (float)h.y * s;
                    o.z = (float)h.z * s; o.w = (float)h.w * s;
                    __builtin_nontemporal_store(o, po + i);
                }
            }
        }
    }
}

// ---------------- fallback: round-4 three-kernel path ----------------
__global__ __launch_bounds__(256) void se_squeeze(const f4* __restrict__ x,
                                                  float* __restrict__ sq) {
    const int wave = threadIdx.x >> 6, lane = threadIdx.x & 63;
    const int base = blockIdx.x * 8 + wave * 2;
    #pragma unroll
    for (int sub = 0; sub < 2; ++sub) {
        const int row = base + sub;
        const f4* p = x + (size_t)row * VEC_PER_ROW;
        float s = 0.f;
        #pragma unroll
        for (int k = 0; k < 13; ++k) {
            const int i = lane + (k << 6);
            if (i < VEC_PER_ROW) { f4 v = p[i]; s += (v.x + v.y) + (v.z + v.w); }
        }
        #pragma unroll
        for (int off = 32; off > 0; off >>= 1) s += __shfl_down(s, off, 64);
        if (lane == 0) sq[row] = s * (1.0f / (float)SPATIAL);
    }
}

__global__ __launch_bounds__(512) void se_excite(const float* __restrict__ sq,
                                                 const float* __restrict__ w1,
                                                 const float* __restrict__ b1,
                                                 const float* __restrict__ w2,
                                                 const float* __restrict__ b2,
                                                 float* __restrict__ e) {
    const int b = blockIdx.x;
    __shared__ float s_lds[SE_C];
    __shared__ float hh[SE_CR];
    const int t = threadIdx.x;
    s_lds[t] = sq[b * SE_C + t];
    __syncthreads();
    if (t < SE_CR) {
        float acc = b1[t];
        const float* wr = w1 + t * SE_C;
        for (int c = 0; c < SE_C; ++c) acc += s_lds[c] * wr[c];
        hh[t] = fmaxf(acc, 0.f);
    }
    __syncthreads();
    {
        float acc = b2[t];
        const float* wr = w2 + t * SE_CR;
        #pragma unroll
        for (int j = 0; j < SE_CR; ++j) acc += hh[j] * wr[j];
        e[b * SE_C + t] = 1.0f / (1.0f + expf(-acc));
    }
}

__global__ __launch_bounds__(256) void se_scale(const f4* __restrict__ x,
                                                const float* __restrict__ e,
                                                f4* __restrict__ out) {
    const int wave = threadIdx.x >> 6, lane = threadIdx.x & 63;
    const int base = blockIdx.x * 8 + wave * 2;
    #pragma unroll
    for (int sub = 0; sub < 2; ++sub) {
        const int row = base + sub;
        const float s = e[row];
        const f4* px = x + (size_t)row * VEC_PER_ROW;
        f4* po = out + (size_t)row * VEC_PER_ROW;
        #pragma unroll
        for (int k = 0; k < 13; ++k) {
            const int i = lane + (k << 6);
            if (i < VEC_PER_ROW) {
                f4 v = __builtin_nontemporal_load(px + i);
                __builtin_nontemporal_store(v * s, po + i);
            }
        }
    }
}

extern "C" void kernel_launch(void* const* d_in, const int* in_sizes, int n_in,
                              void* d_out, int out_size, void* d_ws, size_t ws_size,
                              hipStream_t stream) {
    const f4*    x  = (const f4*)d_in[0];
    const float* w1 = (const float*)d_in[1];
    const float* b1 = (const float*)d_in[2];
    const float* w2 = (const float*)d_in[3];
    const float* b2 = (const float*)d_in[4];
    f4* out = (f4*)d_out;

    float* sq = (float*)d_ws;                 // [16384]
    float* e  = sq + ROWS;                    // [16384] (fallback only)

    static int attr_set = 0;  // host-side setup, not device state; idempotent
    if (!attr_set) {
        hipFuncSetAttribute(reinterpret_cast<const void*>(se_fused),
                            hipFuncAttributeMaxDynamicSharedMemorySize, LDS_TOTAL);
        attr_set = 1;
    }

    void* args[] = {(void*)&x, (void*)&w1, (void*)&b1, (void*)&w2, (void*)&b2,
                    (void*)&sq, (void*)&out};
    hipError_t err = hipLaunchCooperativeKernel(
        reinterpret_cast<void*>(se_fused), dim3(NBLK), dim3(NTHR),
        args, LDS_TOTAL, stream);

    if (err != hipSuccess) {
        // fallback: 3-kernel streaming path (round-4 behavior)
        se_squeeze<<<ROWS / 8, 256, 0, stream>>>(x, sq);
        se_excite<<<32, 512, 0, stream>>>(sq, w1, b1, w2, b2, e);
        se_scale<<<ROWS / 8, 256, 0, stream>>>(x, e, out);
    }
}

// Round 6
// 193.491 us; speedup vs baseline: 1.0861x; 1.0861x over previous
//
#include <hip/hip_runtime.h>
#include <hip/hip_cooperative_groups.h>
#include <math.h>

namespace cg = cooperative_groups;

// SE block: x[32,512,56,56] fp32, fused single-pass cooperative kernel.
// Per CU: 64 rows of x retained on-chip as fp16 (401 KB):
//   3 rows/wave in LDS (24 rows, 150.5 KB) + 5 rows/wave in VGPRs (130 regs).
// Phase 1: read x once (205 MB), fp16-retain, row sums -> sq (global).
// grid.sync() ; Phase 2: tiny FCs -> e (LDS). Phase 3: scale retained x,
// nt-store out (205 MB). HBM total ~411 MB vs 616 MB for the 3-kernel path
// (less with cross-replay L3 retention of x: round-5 measured FETCH=125 MB).
// Round-5 lesson: __launch_bounds__(512,2) made hipcc cap VGPR at 128 ->
// spill catastrophe. Use amdgpu_waves_per_eu(2) => cap 256, need ~200.

#define SE_C 512
#define SE_CR 32
#define SPATIAL 3136
#define VEC_PER_ROW 784          // f4 per (b,c) row
#define ROWS 16384
#define NBLK 256
#define NTHR 512                 // 8 waves
#define ROWS_PER_BLK 64
#define ROWS_PER_WAVE 8
#define LDS_ROWS_PER_WAVE 3
#define REG_ROWS_PER_WAVE 5
#define LDS_ROWS 24              // 8 waves * 3
#define K_FULL 12                // 12*64 = 768 f4; tail f4s 768..783 on lanes 0..15

typedef float f4 __attribute__((ext_vector_type(4)));
typedef _Float16 h4 __attribute__((ext_vector_type(4)));

#define LDS_X_BYTES (LDS_ROWS * VEC_PER_ROW * 8)              // 150528
#define LDS_TOTAL   (LDS_X_BYTES + SE_C*4 + SE_CR*4 + ROWS_PER_BLK*4)  // 152960

__global__ __launch_bounds__(NTHR)
__attribute__((amdgpu_waves_per_eu(2)))
void se_fused(
    const f4* __restrict__ x,
    const float* __restrict__ w1, const float* __restrict__ b1,
    const float* __restrict__ w2, const float* __restrict__ b2,
    float* __restrict__ sq_g, f4* __restrict__ out)
{
    extern __shared__ char smem[];
    h4*    xl     = (h4*)smem;                                  // [24][784]
    float* sq_lds = (float*)(smem + LDS_X_BYTES);               // [512]
    float* h_lds  = sq_lds + SE_C;                              // [32]
    float* e_lds  = h_lds + SE_CR;                              // [64]

    const int t    = threadIdx.x;
    const int wave = t >> 6;
    const int lane = t & 63;
    const int blk  = blockIdx.x;
    const int row0 = blk * ROWS_PER_BLK + wave * ROWS_PER_WAVE;

    h4 rx[REG_ROWS_PER_WAVE][K_FULL + 1];   // statically indexed only (~130 VGPR)

    // ---------------- phase 1: read x once, retain fp16, row sums ----------
    #pragma unroll
    for (int r = 0; r < ROWS_PER_WAVE; ++r) {
        const int row = row0 + r;
        const f4* p = x + (size_t)row * VEC_PER_ROW;
        float s = 0.f;
        if (r < LDS_ROWS_PER_WAVE) {
            h4* q = xl + (size_t)(wave * LDS_ROWS_PER_WAVE + r) * VEC_PER_ROW;
            #pragma unroll
            for (int k = 0; k <= K_FULL; ++k) {
                const int i = lane + (k << 6);
                if (k < K_FULL || lane < 16) {
                    f4 v = p[i];                         // regular load -> L3
                    s += (v.x + v.y) + (v.z + v.w);
                    h4 h;
                    h.x = (_Float16)v.x; h.y = (_Float16)v.y;
                    h.z = (_Float16)v.z; h.w = (_Float16)v.w;
                    q[i] = h;
                }
            }
        } else {
            const int rr = r - LDS_ROWS_PER_WAVE;        // 0..4 static
            #pragma unroll
            for (int k = 0; k <= K_FULL; ++k) {
                const int i = lane + (k << 6);
                if (k < K_FULL || lane < 16) {
                    f4 v = p[i];
                    s += (v.x + v.y) + (v.z + v.w);
                    h4 h;
                    h.x = (_Float16)v.x; h.y = (_Float16)v.y;
                    h.z = (_Float16)v.z; h.w = (_Float16)v.w;
                    rx[rr][k] = h;
                }
            }
        }
        #pragma unroll
        for (int off = 32; off > 0; off >>= 1) s += __shfl_down(s, off, 64);
        if (lane == 0) sq_g[row] = s * (1.0f / (float)SPATIAL);
    }

    // sq must be visible across XCDs after the grid barrier
    __builtin_amdgcn_fence(__ATOMIC_RELEASE, "agent");
    cg::this_grid().sync();
    __builtin_amdgcn_fence(__ATOMIC_ACQUIRE, "agent");

    // ---------------- phase 2: excitation (redundant per block) ------------
    const int b = blk >> 3;                     // batch of this block's rows
    sq_lds[t] = sq_g[b * SE_C + t];
    __syncthreads();
    if (t < SE_CR) {
        float acc = b1[t];
        const float* wr = w1 + t * SE_C;
        #pragma unroll 8
        for (int c = 0; c < SE_C; ++c) acc += sq_lds[c] * wr[c];
        h_lds[t] = fmaxf(acc, 0.f);
    }
    __syncthreads();
    if (t < ROWS_PER_BLK) {
        const int c = (blk & 7) * ROWS_PER_BLK + t;   // channel of local row t
        float acc = b2[c];
        const float* wr = w2 + c * SE_CR;
        #pragma unroll
        for (int j = 0; j < SE_CR; ++j) acc += h_lds[j] * wr[j];
        e_lds[t] = 1.0f / (1.0f + expf(-acc));
    }
    __syncthreads();

    // ---------------- phase 3: scale retained x, nt-store out --------------
    #pragma unroll
    for (int r = 0; r < ROWS_PER_WAVE; ++r) {
        const int row = row0 + r;
        const float s = e_lds[wave * ROWS_PER_WAVE + r];
        f4* po = out + (size_t)row * VEC_PER_ROW;
        if (r < LDS_ROWS_PER_WAVE) {
            const h4* q = xl + (size_t)(wave * LDS_ROWS_PER_WAVE + r) * VEC_PER_ROW;
            #pragma unroll
            for (int k = 0; k <= K_FULL; ++k) {
                const int i = lane + (k << 6);
                if (k < K_FULL || lane < 16) {
                    h4 h = q[i];
                    f4 o;
                    o.x = (float)h.x * s; o.y = (float)h.y * s;
                    o.z = (float)h.z * s; o.w = (float)h.w * s;
                    __builtin_nontemporal_store(o, po + i);
                }
            }
        } else {
            const int rr = r - LDS_ROWS_PER_WAVE;
            #pragma unroll
            for (int k = 0; k <= K_FULL; ++k) {
                const int i = lane + (k << 6);
                if (k < K_FULL || lane < 16) {
                    h4 h = rx[rr][k];
                    f4 o;
                    o.x = (float)h.x * s; o.y = (float)h.y * s;
                    o.z = (float)h.z * s; o.w = (float)h.w * s;
                    __builtin_nontemporal_store(o, po + i);
                }
            }
        }
    }
}

// ---------------- fallback: round-4 three-kernel path ----------------
__global__ __launch_bounds__(256) void se_squeeze(const f4* __restrict__ x,
                                                  float* __restrict__ sq) {
    const int wave = threadIdx.x >> 6, lane = threadIdx.x & 63;
    const int base = blockIdx.x * 8 + wave * 2;
    #pragma unroll
    for (int sub = 0; sub < 2; ++sub) {
        const int row = base + sub;
        const f4* p = x + (size_t)row * VEC_PER_ROW;
        float s = 0.f;
        #pragma unroll
        for (int k = 0; k < 13; ++k) {
            const int i = lane + (k << 6);
            if (i < VEC_PER_ROW) { f4 v = p[i]; s += (v.x + v.y) + (v.z + v.w); }
        }
        #pragma unroll
        for (int off = 32; off > 0; off >>= 1) s += __shfl_down(s, off, 64);
        if (lane == 0) sq[row] = s * (1.0f / (float)SPATIAL);
    }
}

__global__ __launch_bounds__(512) void se_excite(const float* __restrict__ sq,
                                                 const float* __restrict__ w1,
                                                 const float* __restrict__ b1,
                                                 const float* __restrict__ w2,
                                                 const float* __restrict__ b2,
                                                 float* __restrict__ e) {
    const int b = blockIdx.x;
    __shared__ float s_lds[SE_C];
    __shared__ float hh[SE_CR];
    const int t = threadIdx.x;
    s_lds[t] = sq[b * SE_C + t];
    __syncthreads();
    if (t < SE_CR) {
        float acc = b1[t];
        const float* wr = w1 + t * SE_C;
        for (int c = 0; c < SE_C; ++c) acc += s_lds[c] * wr[c];
        hh[t] = fmaxf(acc, 0.f);
    }
    __syncthreads();
    {
        float acc = b2[t];
        const float* wr = w2 + t * SE_CR;
        #pragma unroll
        for (int j = 0; j < SE_CR; ++j) acc += hh[j] * wr[j];
        e[b * SE_C + t] = 1.0f / (1.0f + expf(-acc));
    }
}

__global__ __launch_bounds__(256) void se_scale(const f4* __restrict__ x,
                                                const float* __restrict__ e,
                                                f4* __restrict__ out) {
    const int wave = threadIdx.x >> 6, lane = threadIdx.x & 63;
    const int base = blockIdx.x * 8 + wave * 2;
    #pragma unroll
    for (int sub = 0; sub < 2; ++sub) {
        const int row = base + sub;
        const float s = e[row];
        const f4* px = x + (size_t)row * VEC_PER_ROW;
        f4* po = out + (size_t)row * VEC_PER_ROW;
        #pragma unroll
        for (int k = 0; k < 13; ++k) {
            const int i = lane + (k << 6);
            if (i < VEC_PER_ROW) {
                f4 v = __builtin_nontemporal_load(px + i);
                __builtin_nontemporal_store(v * s, po + i);
            }
        }
    }
}

extern "C" void kernel_launch(void* const* d_in, const int* in_sizes, int n_in,
                              void* d_out, int out_size, void* d_ws, size_t ws_size,
                              hipStream_t stream) {
    const f4*    x  = (const f4*)d_in[0];
    const float* w1 = (const float*)d_in[1];
    const float* b1 = (const float*)d_in[2];
    const float* w2 = (const float*)d_in[3];
    const float* b2 = (const float*)d_in[4];
    f4* out = (f4*)d_out;

    float* sq = (float*)d_ws;                 // [16384]
    float* e  = sq + ROWS;                    // [16384] (fallback only)

    static int attr_set = 0;  // host-side config, idempotent, not device state
    if (!attr_set) {
        hipFuncSetAttribute(reinterpret_cast<const void*>(se_fused),
                            hipFuncAttributeMaxDynamicSharedMemorySize, LDS_TOTAL);
        attr_set = 1;
    }

    void* args[] = {(void*)&x, (void*)&w1, (void*)&b1, (void*)&w2, (void*)&b2,
                    (void*)&sq, (void*)&out};
    hipError_t err = hipLaunchCooperativeKernel(
        reinterpret_cast<void*>(se_fused), dim3(NBLK), dim3(NTHR),
        args, LDS_TOTAL, stream);

    if (err != hipSuccess) {
        // fallback: 3-kernel streaming path (round-4 behavior, ~107 us)
        se_squeeze<<<ROWS / 8, 256, 0, stream>>>(x, sq);
        se_excite<<<32, 512, 0, stream>>>(sq, w1, b1, w2, b2, e);
        se_scale<<<ROWS / 8, 256, 0, stream>>>(x, e, out);
    }
}

// Round 7
// 107.220 us; speedup vs baseline: 1.9600x; 1.8046x over previous
//
#include <hip/hip_runtime.h>
#include <math.h>

// SE block: x[32,512,56,56] fp32.
//   squeeze = mean over (H,W) -> [32,512]
//   e = sigmoid(relu(squeeze@w1^T+b1)@w2^T + b2)
//   out = x * e[b,c]
//
// Round 5/6 evidence: L3 (256 MB) retains x and serves re-reads (FETCH 113 MB
// < 205 MB), but a full-x pass self-evicts (205 MB ~ capacity). Fix: process
// 16-batch chunks (103 MB). squeeze(chunk) fills L3; scale(chunk) re-reads it
// hot (nt out-stores don't evict) -> HBM traffic ~ 205r + 205w = 410 MB.
// Excite folded into scale prologue (redundant per block, overlapped).
// No cooperative launch, no big VGPR arrays (rounds 5/6: hipcc caps at 128
// and spills catastrophically).

#define SE_C 512
#define SE_CR 32
#define SE_B 32
#define SPATIAL 3136
#define VEC_PER_ROW 784            // f4 per (b,c) row
#define ROWS 16384
#define CHUNK_B 16                 // batches per chunk
#define CHUNK_ROWS (CHUNK_B * SE_C)  // 8192

typedef float f4 __attribute__((ext_vector_type(4)));

// ---------------- squeeze over one chunk ----------------
// 1024 blocks x 256 thr; wave handles 2 rows. Regular loads: allocate in L3.
__global__ __launch_bounds__(256) void se_squeeze(const f4* __restrict__ x,
                                                  float* __restrict__ sq,
                                                  int row_base) {
    const int wave = threadIdx.x >> 6, lane = threadIdx.x & 63;
    const int base = row_base + blockIdx.x * 8 + wave * 2;
    #pragma unroll
    for (int sub = 0; sub < 2; ++sub) {
        const int row = base + sub;
        const f4* p = x + (size_t)row * VEC_PER_ROW;
        float s = 0.f;
        #pragma unroll
        for (int k = 0; k < 13; ++k) {          // 13*64 = 832 >= 784
            const int i = lane + (k << 6);
            if (i < VEC_PER_ROW) {
                f4 v = p[i];
                s += (v.x + v.y) + (v.z + v.w);
            }
        }
        #pragma unroll
        for (int off = 32; off > 0; off >>= 1) s += __shfl_down(s, off, 64);
        if (lane == 0) sq[row] = s * (1.0f / (float)SPATIAL);
    }
}

// ---------------- excite + scale over one chunk ----------------
// 1024 blocks x 256 thr; block = 8 consecutive channels of ONE batch.
// Prologue: redundant per-block excite (FC1 parallel: 32 outs x 8 thr x 64
// MACs + shfl_xor reduce; FC2: 32 MACs per row). Then stream-scale the 8
// rows: x reads hit L3 (chunk is hot), out nt-stored.
__global__ __launch_bounds__(256) void se_scale_ex(
    const f4* __restrict__ x, const float* __restrict__ sq,
    const float* __restrict__ w1, const float* __restrict__ b1,
    const float* __restrict__ w2, const float* __restrict__ b2,
    f4* __restrict__ out, int row_base) {
    __shared__ float s_lds[SE_C];
    __shared__ float h_lds[SE_CR];
    const int t = threadIdx.x;
    const int wave = t >> 6, lane = t & 63;
    const int brow = row_base + blockIdx.x * 8;   // 8 rows, same batch
    const int b = brow >> 9;                      // row / 512

    // stage sq[b, :] (512 floats)
    s_lds[t]       = sq[(b << 9) + t];
    s_lds[t + 256] = sq[(b << 9) + t + 256];
    __syncthreads();

    // FC1 + relu: output j computed by threads t = j*8 .. j*8+7
    {
        const int j = t >> 3, g = t & 7;
        const float* wr = w1 + j * SE_C + (g << 6);
        const float* sr = s_lds + (g << 6);
        float p = 0.f;
        #pragma unroll
        for (int m = 0; m < 64; ++m) p += sr[m] * wr[m];
        p += __shfl_xor(p, 1, 8);
        p += __shfl_xor(p, 2, 8);
        p += __shfl_xor(p, 4, 8);
        if (g == 0) h_lds[j] = fmaxf(p + b1[j], 0.f);
    }
    __syncthreads();

    // per wave: 2 rows; FC2 + sigmoid redundantly per lane (32 MACs), then scale
    #pragma unroll
    for (int sub = 0; sub < 2; ++sub) {
        const int row = brow + wave * 2 + sub;
        const int c = row & 511;                  // channel
        float acc = b2[c];
        const float* wr = w2 + c * SE_CR;
        #pragma unroll
        for (int j = 0; j < SE_CR; ++j) acc += h_lds[j] * wr[j];
        const float s = 1.0f / (1.0f + expf(-acc));

        const f4* px = x + (size_t)row * VEC_PER_ROW;
        f4* po = out + (size_t)row * VEC_PER_ROW;
        #pragma unroll
        for (int k = 0; k < 13; ++k) {
            const int i = lane + (k << 6);
            if (i < VEC_PER_ROW) {
                f4 v = __builtin_nontemporal_load(px + i);  // hit L3; no re-alloc on miss
                __builtin_nontemporal_store(v * s, po + i);
            }
        }
    }
}

extern "C" void kernel_launch(void* const* d_in, const int* in_sizes, int n_in,
                              void* d_out, int out_size, void* d_ws, size_t ws_size,
                              hipStream_t stream) {
    const f4*    x  = (const f4*)d_in[0];
    const float* w1 = (const float*)d_in[1];
    const float* b1 = (const float*)d_in[2];
    const float* w2 = (const float*)d_in[3];
    const float* b2 = (const float*)d_in[4];
    f4* out = (f4*)d_out;

    float* sq = (float*)d_ws;                 // [16384]

    const int blocks_per_chunk = CHUNK_ROWS / 8;   // 1024
    for (int chunk = 0; chunk < ROWS / CHUNK_ROWS; ++chunk) {
        const int row_base = chunk * CHUNK_ROWS;
        se_squeeze<<<blocks_per_chunk, 256, 0, stream>>>(x, sq, row_base);
        se_scale_ex<<<blocks_per_chunk, 256, 0, stream>>>(x, sq, w1, b1, w2, b2,
                                                          out, row_base);
    }
}

// Round 8
// 98.909 us; speedup vs baseline: 2.1247x; 1.0840x over previous
//
#include <hip/hip_runtime.h>
#include <math.h>

// SE block: x[32,512,56,56] fp32.
//   squeeze = mean over (H,W) -> [32,512]
//   e = sigmoid(relu(squeeze@w1^T+b1)@w2^T + b2)
//   out = x * e[b,c]
//
// Machine law established rounds 2-7: all global traffic ~6-7 TB/s regardless
// of L3/L2 residency games (chunking, shadows, retention all neutral-to-worse;
// on-chip retention loses occupancy needed to stream). Floor = 616 MB
// (205 read + 205 re-read + 205 write) / ~6.3 TB/s ~= 100 us.
// This round: best-known config (plain loads + nt stores), excite folded into
// scale prologue, 2 launches.

#define SE_C 512
#define SE_CR 32
#define SPATIAL 3136
#define VEC_PER_ROW 784            // f4 per (b,c) row
#define ROWS 16384

typedef float f4 __attribute__((ext_vector_type(4)));

// ---------------- Kernel 1: squeeze ----------------
// 2048 blocks x 256 thr; each wave reduces 2 rows. Plain loads.
__global__ __launch_bounds__(256) void se_squeeze(const f4* __restrict__ x,
                                                  float* __restrict__ sq) {
    const int wave = threadIdx.x >> 6, lane = threadIdx.x & 63;
    const int base = blockIdx.x * 8 + wave * 2;
    #pragma unroll
    for (int sub = 0; sub < 2; ++sub) {
        const int row = base + sub;
        const f4* p = x + (size_t)row * VEC_PER_ROW;
        float s = 0.f;
        #pragma unroll
        for (int k = 0; k < 13; ++k) {          // 12 full + 16-lane tail
            const int i = lane + (k << 6);
            if (i < VEC_PER_ROW) {
                f4 v = p[i];
                s += (v.x + v.y) + (v.z + v.w);
            }
        }
        #pragma unroll
        for (int off = 32; off > 0; off >>= 1) s += __shfl_down(s, off, 64);
        if (lane == 0) sq[row] = s * (1.0f / (float)SPATIAL);
    }
}

// ---------------- Kernel 2: excite (folded) + scale ----------------
// 2048 blocks x 256 thr; block = 8 consecutive channels of ONE batch
// (64 blocks per batch). Prologue: redundant per-block excite
// (FC1: 32 outs x 8 thr x 64 MACs + shfl reduce; FC2: 32 MACs per row).
// Main: stream-scale 2 rows per wave. Plain x loads (round-4 A/B: nt loads
// cost ~1.5us), nt out stores (round-2 A/B: nt stores gain ~12us).
__global__ __launch_bounds__(256) void se_scale_ex(
    const f4* __restrict__ x, const float* __restrict__ sq,
    const float* __restrict__ w1, const float* __restrict__ b1,
    const float* __restrict__ w2, const float* __restrict__ b2,
    f4* __restrict__ out) {
    __shared__ float s_lds[SE_C];
    __shared__ float h_lds[SE_CR];
    const int t = threadIdx.x;
    const int wave = t >> 6, lane = t & 63;
    const int brow = blockIdx.x * 8;              // 8 rows, same batch
    const int b = brow >> 9;                      // batch = row / 512

    // stage sq[b, :] (512 floats)
    s_lds[t]       = sq[(b << 9) + t];
    s_lds[t + 256] = sq[(b << 9) + t + 256];
    __syncthreads();

    // FC1 + relu: output j computed by threads t = j*8 .. j*8+7
    {
        const int j = t >> 3, g = t & 7;
        const float* wr = w1 + j * SE_C + (g << 6);
        const float* sr = s_lds + (g << 6);
        float p = 0.f;
        #pragma unroll
        for (int m = 0; m < 64; ++m) p += sr[m] * wr[m];
        p += __shfl_xor(p, 1, 8);
        p += __shfl_xor(p, 2, 8);
        p += __shfl_xor(p, 4, 8);
        if (g == 0) h_lds[j] = fmaxf(p + b1[j], 0.f);
    }
    __syncthreads();

    // per wave: 2 rows; FC2 + sigmoid redundantly per lane, then scale
    #pragma unroll
    for (int sub = 0; sub < 2; ++sub) {
        const int row = brow + wave * 2 + sub;
        const int c = row & 511;                  // channel
        float acc = b2[c];
        const float* wr = w2 + c * SE_CR;
        #pragma unroll
        for (int j = 0; j < SE_CR; ++j) acc += h_lds[j] * wr[j];
        const float s = 1.0f / (1.0f + expf(-acc));

        const f4* px = x + (size_t)row * VEC_PER_ROW;
        f4* po = out + (size_t)row * VEC_PER_ROW;
        #pragma unroll
        for (int k = 0; k < 13; ++k) {
            const int i = lane + (k << 6);
            if (i < VEC_PER_ROW) {
                f4 v = px[i];                          // plain load
                __builtin_nontemporal_store(v * s, po + i);
            }
        }
    }
}

extern "C" void kernel_launch(void* const* d_in, const int* in_sizes, int n_in,
                              void* d_out, int out_size, void* d_ws, size_t ws_size,
                              hipStream_t stream) {
    const f4*    x  = (const f4*)d_in[0];
    const float* w1 = (const float*)d_in[1];
    const float* b1 = (const float*)d_in[2];
    const float* w2 = (const float*)d_in[3];
    const float* b2 = (const float*)d_in[4];
    f4* out = (f4*)d_out;

    float* sq = (float*)d_ws;                 // [16384]

    se_squeeze<<<ROWS / 8, 256, 0, stream>>>(x, sq);
    se_scale_ex<<<ROWS / 8, 256, 0, stream>>>(x, sq, w1, b1, w2, b2, out);
}